// Round 1
// baseline (3616.545 us; speedup 1.0000x reference)
//
#include <hip/hip_runtime.h>

#define N_USERS 100000
#define N_ITEMS 50001
#define N_EDGES 1000000
#define D 64
#define BATCH 4096
#define MAXLEN 50

// dst[didx[e]] += val[e] * src[sidx[e]]   (rows of D floats)
// one thread per (edge, float4-chunk): 16 chunks/edge
__global__ __launch_bounds__(256) void spmm_kernel(
    const float* __restrict__ src, const float* __restrict__ val,
    const int* __restrict__ sidx, const int* __restrict__ didx,
    float* __restrict__ dst)
{
    int t = blockIdx.x * 256 + threadIdx.x;
    int e = t >> 4;
    int c = t & 15;
    if (e >= N_EDGES) return;
    int si = sidx[e];
    int di = didx[e];
    float v = val[e];
    float4 x = ((const float4*)(src + (size_t)si * D))[c];
    float* drow = dst + (size_t)di * D + (size_t)c * 4;
    unsafeAtomicAdd(drow + 0, v * x.x);
    unsafeAtomicAdd(drow + 1, v * x.y);
    unsafeAtomicAdd(drow + 2, v * x.z);
    unsafeAtomicAdd(drow + 3, v * x.w);
}

// Vf = (V0 + V1 + V2)/3 + V0
__global__ __launch_bounds__(256) void combine_kernel(
    const float* __restrict__ V0, const float* __restrict__ V1,
    const float* __restrict__ V2, float* __restrict__ Vf)
{
    int i = blockIdx.x * 256 + threadIdx.x;
    if (i < N_ITEMS * D) {
        float v0 = V0[i];
        Vf[i] = (v0 + V1[i] + V2[i]) * (1.0f / 3.0f) + v0;
    }
}

__device__ __forceinline__ float wave_sum64(float v) {
#pragma unroll
    for (int o = 1; o < 64; o <<= 1) v += __shfl_xor(v, o, 64);
    return v;
}

// attention pooling: 4 waves/block, one batch element per wave.
// lane e keeps row e of W_att and W_agg in registers.
__global__ __launch_bounds__(256) void phase2_kernel(
    const float* __restrict__ user_table, const float* __restrict__ Vf,
    const float* __restrict__ Watt, const float* __restrict__ Wb,
    const float* __restrict__ Wagg, const int* __restrict__ uidx,
    const int* __restrict__ ctx, float* __restrict__ out)
{
    __shared__ __align__(16) float seqrow[4][64];
    __shared__ __align__(16) float xbuf[4][64];
    __shared__ __align__(16) float pooled_s[4][64];
    __shared__ int idxbuf[4][MAXLEN];

    const int tid = threadIdx.x;
    const int w = tid >> 6;
    const int lane = tid & 63;
    const int b = blockIdx.x * 4 + w;

    // register-resident W rows (lane e holds row e)
    float wa[D], wg[D];
    {
        const float4* wr = (const float4*)(Watt + (size_t)lane * D);
        const float4* gr = (const float4*)(Wagg + (size_t)lane * D);
#pragma unroll
        for (int k = 0; k < 16; ++k) {
            float4 a = wr[k];
            float4 g = gr[k];
            wa[4 * k + 0] = a.x; wa[4 * k + 1] = a.y;
            wa[4 * k + 2] = a.z; wa[4 * k + 3] = a.w;
            wg[4 * k + 0] = g.x; wg[4 * k + 1] = g.y;
            wg[4 * k + 2] = g.z; wg[4 * k + 3] = g.w;
        }
    }
    float bias = Wb[lane];
    int uid = uidx[b];
    float id_e = user_table[(size_t)uid * D + lane];

    // pass A: X[l] = mask ? 0 : sum_e tanh(seq . Watt[e] + b[e]) * id_emb[e]
    for (int l = 0; l < MAXLEN; ++l) {
        int ci = ctx[b * MAXLEN + l];
        if (lane == 0) idxbuf[w][l] = ci;
        float s = Vf[(size_t)ci * D + lane];
        seqrow[w][lane] = s;
        // wave-synchronous: write above completes for all 64 lanes before the
        // reads below issue (single instruction stream; compiler emits lgkmcnt)
        float acc0 = bias, acc1 = 0.f, acc2 = 0.f, acc3 = 0.f;
#pragma unroll
        for (int d = 0; d < D; d += 4) {
            float4 s4 = *(const float4*)&seqrow[w][d];
            acc0 += s4.x * wa[d + 0];
            acc1 += s4.y * wa[d + 1];
            acc2 += s4.z * wa[d + 2];
            acc3 += s4.w * wa[d + 3];
        }
        float key = tanhf(acc0 + acc1 + acc2 + acc3);
        float part = key * id_e;
        float rs = s;
        float att = part;
#pragma unroll
        for (int o = 1; o < 64; o <<= 1) {
            att += __shfl_xor(att, o, 64);
            rs += __shfl_xor(rs, o, 64);
        }
        float X = (rs == 0.0f) ? 0.0f : att;
        if (lane == 0) xbuf[w][l] = X;
    }

    // softmax over l (reference: exp without max-subtraction, +1e-12 in denom)
    float ex = (lane < MAXLEN) ? expf(xbuf[w][lane]) : 0.0f;
    float denom = wave_sum64(ex) + 1e-12f;
    if (lane < MAXLEN) xbuf[w][lane] = ex / denom;

    // pass B: pooled[d] = sum_l attn[l] * seq[l][d]
    float pooled = 0.0f;
    for (int l = 0; l < MAXLEN; ++l) {
        int ci = idxbuf[w][l];
        float a = xbuf[w][l];
        pooled += a * Vf[(size_t)ci * D + lane];
    }
    pooled_s[w][lane] = pooled;

    // out[e] = pooled . Wagg[e]
    float o0 = 0.f, o1 = 0.f, o2 = 0.f, o3 = 0.f;
#pragma unroll
    for (int d = 0; d < D; d += 4) {
        float4 p4 = *(const float4*)&pooled_s[w][d];
        o0 += p4.x * wg[d + 0];
        o1 += p4.y * wg[d + 1];
        o2 += p4.z * wg[d + 2];
        o3 += p4.w * wg[d + 3];
    }
    float outv = o0 + o1 + o2 + o3;
    out[(size_t)b * D + lane] = 0.5f * id_e + 0.5f * outv;
}

extern "C" void kernel_launch(void* const* d_in, const int* in_sizes, int n_in,
                              void* d_out, int out_size, void* d_ws, size_t ws_size,
                              hipStream_t stream)
{
    const float* user_table = (const float*)d_in[0];
    const float* item_table = (const float*)d_in[1];
    const float* ev_uv      = (const float*)d_in[2];
    const float* ev_vu      = (const float*)d_in[3];
    const float* Watt       = (const float*)d_in[4];
    const float* Wb         = (const float*)d_in[5];
    const float* Wagg       = (const float*)d_in[6];
    const int*   edge_u     = (const int*)d_in[7];
    const int*   edge_i     = (const int*)d_in[8];
    const int*   uidx       = (const int*)d_in[9];
    const int*   ctx        = (const int*)d_in[10];
    float* out = (float*)d_out;

    float* u_msg = (float*)d_ws;                       // [N_USERS, D]
    float* V1 = u_msg + (size_t)N_USERS * D;           // [N_ITEMS, D]
    float* V2 = V1 + (size_t)N_ITEMS * D;              // [N_ITEMS, D]
    float* Vf = V2 + (size_t)N_ITEMS * D;              // [N_ITEMS, D]

    // zero u_msg, V1, V2 (contiguous)
    hipMemsetAsync(u_msg, 0,
                   ((size_t)N_USERS + 2 * (size_t)N_ITEMS) * D * sizeof(float),
                   stream);

    const int spmm_blocks = (N_EDGES * 16 + 255) / 256;

    // layer 1: u_msg = seg_sum(ev_uv * V0[edge_i], edge_u); V1 = seg_sum(ev_vu * u_msg[edge_u], edge_i)
    spmm_kernel<<<spmm_blocks, 256, 0, stream>>>(item_table, ev_uv, edge_i, edge_u, u_msg);
    spmm_kernel<<<spmm_blocks, 256, 0, stream>>>(u_msg, ev_vu, edge_u, edge_i, V1);

    // layer 2
    hipMemsetAsync(u_msg, 0, (size_t)N_USERS * D * sizeof(float), stream);
    spmm_kernel<<<spmm_blocks, 256, 0, stream>>>(V1, ev_uv, edge_i, edge_u, u_msg);
    spmm_kernel<<<spmm_blocks, 256, 0, stream>>>(u_msg, ev_vu, edge_u, edge_i, V2);

    // Vf = (V0+V1+V2)/3 + V0
    combine_kernel<<<(N_ITEMS * D + 255) / 256, 256, 0, stream>>>(item_table, V1, V2, Vf);

    // attention pooling + output
    phase2_kernel<<<BATCH / 4, 256, 0, stream>>>(user_table, Vf, Watt, Wb, Wagg,
                                                 uidx, ctx, out);
}

// Round 2
// 740.389 us; speedup vs baseline: 4.8847x; 4.8847x over previous
//
#include <hip/hip_runtime.h>

#define N_USERS 100000
#define N_ITEMS 50001
#define N_EDGES 1000000
#define D 64
#define BATCH 4096
#define MAXLEN 50

// ---------------- CSR build ----------------

__global__ __launch_bounds__(256) void hist_kernel(
    const int* __restrict__ eu, const int* __restrict__ ei,
    int* __restrict__ cnt_u, int* __restrict__ cnt_i)
{
    int e = blockIdx.x * 256 + threadIdx.x;
    if (e < N_EDGES) {
        atomicAdd(&cnt_u[eu[e]], 1);
        atomicAdd(&cnt_i[ei[e]], 1);
    }
}

// bump-allocate contiguous segments per row (order-free "scan"):
// one atomic per wave; cnt[] becomes the running cursor (cur), off[] the base.
__global__ __launch_bounds__(256) void offsets_kernel(
    int* __restrict__ cnt /* in: counts, out: cursor */,
    int* __restrict__ off, int n, unsigned int* __restrict__ alloc_ctr)
{
    int i = blockIdx.x * 256 + threadIdx.x;
    int lane = threadIdx.x & 63;
    int c = (i < n) ? cnt[i] : 0;
    // inclusive prefix within wave
    int pre = c;
#pragma unroll
    for (int o = 1; o < 64; o <<= 1) {
        int t = __shfl_up(pre, o, 64);
        if (lane >= o) pre += t;
    }
    int wave_total = __shfl(pre, 63, 64);
    unsigned int base = 0;
    if (lane == 63) base = atomicAdd(alloc_ctr, (unsigned int)wave_total);
    base = __shfl((int)base, 63, 64);
    int my_off = (int)base + pre - c;  // exclusive
    if (i < n) {
        off[i] = my_off;
        cnt[i] = my_off;  // becomes cursor for scatter
    }
}

__global__ __launch_bounds__(256) void scatter_kernel(
    const int* __restrict__ eu, const int* __restrict__ ei,
    const float* __restrict__ ev_uv, const float* __restrict__ ev_vu,
    int* __restrict__ cur_u, int* __restrict__ cur_i,
    int* __restrict__ csr_u_idx, float* __restrict__ csr_u_val,
    int* __restrict__ csr_i_idx, float* __restrict__ csr_i_val)
{
    int e = blockIdx.x * 256 + threadIdx.x;
    if (e < N_EDGES) {
        int u = eu[e], it = ei[e];
        int pu = atomicAdd(&cur_u[u], 1);
        csr_u_idx[pu] = it;
        csr_u_val[pu] = ev_uv[e];
        int pi = atomicAdd(&cur_i[it], 1);
        csr_i_idx[pi] = u;
        csr_i_val[pi] = ev_vu[e];
    }
}

// ---------------- gather spmm (no atomics) ----------------
// one wave per destination row, lane = feature dim
__global__ __launch_bounds__(256) void gather_kernel(
    const float* __restrict__ src,
    const int* __restrict__ csr_idx, const float* __restrict__ csr_val,
    const int* __restrict__ off, const int* __restrict__ cur,
    float* __restrict__ dst, int nrows)
{
    int w = (blockIdx.x * 256 + threadIdx.x) >> 6;
    int lane = threadIdx.x & 63;
    if (w >= nrows) return;
    int o = off[w], e = cur[w];
    float acc = 0.0f;
    for (int base = o; base < e; base += 64) {
        int n = min(64, e - base);
        int si = 0; float sv = 0.0f;
        if (lane < n) {
            si = csr_idx[base + lane];
            sv = csr_val[base + lane];
        }
        for (int j = 0; j < n; ++j) {
            int r = __shfl(si, j, 64);
            float v = __shfl(sv, j, 64);
            acc += v * src[(size_t)r * D + lane];
        }
    }
    dst[(size_t)w * D + lane] = acc;
}

// final pass: V2-gather fused with Vf = (V0+V1+V2)/3 + V0, written in place over V1
__global__ __launch_bounds__(256) void gather_final_kernel(
    const float* __restrict__ src,
    const int* __restrict__ csr_idx, const float* __restrict__ csr_val,
    const int* __restrict__ off, const int* __restrict__ cur,
    const float* __restrict__ V0, float* __restrict__ V1)
{
    int w = (blockIdx.x * 256 + threadIdx.x) >> 6;
    int lane = threadIdx.x & 63;
    if (w >= N_ITEMS) return;
    int o = off[w], e = cur[w];
    float acc = 0.0f;
    for (int base = o; base < e; base += 64) {
        int n = min(64, e - base);
        int si = 0; float sv = 0.0f;
        if (lane < n) {
            si = csr_idx[base + lane];
            sv = csr_val[base + lane];
        }
        for (int j = 0; j < n; ++j) {
            int r = __shfl(si, j, 64);
            float v = __shfl(sv, j, 64);
            acc += v * src[(size_t)r * D + lane];
        }
    }
    size_t p = (size_t)w * D + lane;
    float v0 = V0[p];
    float v1 = V1[p];
    V1[p] = (v0 + v1 + acc) * (1.0f / 3.0f) + v0;
}

// ---------------- attention pooling ----------------

__device__ __forceinline__ float wave_sum64(float v) {
#pragma unroll
    for (int o = 1; o < 64; o <<= 1) v += __shfl_xor(v, o, 64);
    return v;
}

__global__ __launch_bounds__(256) void phase2_kernel(
    const float* __restrict__ user_table, const float* __restrict__ Vf,
    const float* __restrict__ Watt, const float* __restrict__ Wb,
    const float* __restrict__ Wagg, const int* __restrict__ uidx,
    const int* __restrict__ ctx, float* __restrict__ out)
{
    __shared__ __align__(16) float seqrow[4][64];
    __shared__ __align__(16) float xbuf[4][64];
    __shared__ __align__(16) float pooled_s[4][64];
    __shared__ int idxbuf[4][MAXLEN];

    const int tid = threadIdx.x;
    const int w = tid >> 6;
    const int lane = tid & 63;
    const int b = blockIdx.x * 4 + w;

    float wa[D], wg[D];
    {
        const float4* wr = (const float4*)(Watt + (size_t)lane * D);
        const float4* gr = (const float4*)(Wagg + (size_t)lane * D);
#pragma unroll
        for (int k = 0; k < 16; ++k) {
            float4 a = wr[k];
            float4 g = gr[k];
            wa[4 * k + 0] = a.x; wa[4 * k + 1] = a.y;
            wa[4 * k + 2] = a.z; wa[4 * k + 3] = a.w;
            wg[4 * k + 0] = g.x; wg[4 * k + 1] = g.y;
            wg[4 * k + 2] = g.z; wg[4 * k + 3] = g.w;
        }
    }
    float bias = Wb[lane];
    int uid = uidx[b];
    float id_e = user_table[(size_t)uid * D + lane];

    for (int l = 0; l < MAXLEN; ++l) {
        int ci = ctx[b * MAXLEN + l];
        if (lane == 0) idxbuf[w][l] = ci;
        float s = Vf[(size_t)ci * D + lane];
        seqrow[w][lane] = s;
        float acc0 = bias, acc1 = 0.f, acc2 = 0.f, acc3 = 0.f;
#pragma unroll
        for (int d = 0; d < D; d += 4) {
            float4 s4 = *(const float4*)&seqrow[w][d];
            acc0 += s4.x * wa[d + 0];
            acc1 += s4.y * wa[d + 1];
            acc2 += s4.z * wa[d + 2];
            acc3 += s4.w * wa[d + 3];
        }
        float key = tanhf(acc0 + acc1 + acc2 + acc3);
        float part = key * id_e;
        float rs = s;
        float att = part;
#pragma unroll
        for (int o = 1; o < 64; o <<= 1) {
            att += __shfl_xor(att, o, 64);
            rs += __shfl_xor(rs, o, 64);
        }
        float X = (rs == 0.0f) ? 0.0f : att;
        if (lane == 0) xbuf[w][l] = X;
    }

    float ex = (lane < MAXLEN) ? expf(xbuf[w][lane]) : 0.0f;
    float denom = wave_sum64(ex) + 1e-12f;
    if (lane < MAXLEN) xbuf[w][lane] = ex / denom;

    float pooled = 0.0f;
    for (int l = 0; l < MAXLEN; ++l) {
        int ci = idxbuf[w][l];
        float a = xbuf[w][l];
        pooled += a * Vf[(size_t)ci * D + lane];
    }
    pooled_s[w][lane] = pooled;

    float o0 = 0.f, o1 = 0.f, o2 = 0.f, o3 = 0.f;
#pragma unroll
    for (int d = 0; d < D; d += 4) {
        float4 p4 = *(const float4*)&pooled_s[w][d];
        o0 += p4.x * wg[d + 0];
        o1 += p4.y * wg[d + 1];
        o2 += p4.z * wg[d + 2];
        o3 += p4.w * wg[d + 3];
    }
    float outv = o0 + o1 + o2 + o3;
    out[(size_t)b * D + lane] = 0.5f * id_e + 0.5f * outv;
}

// ---------------- launch ----------------

extern "C" void kernel_launch(void* const* d_in, const int* in_sizes, int n_in,
                              void* d_out, int out_size, void* d_ws, size_t ws_size,
                              hipStream_t stream)
{
    const float* user_table = (const float*)d_in[0];
    const float* item_table = (const float*)d_in[1];
    const float* ev_uv      = (const float*)d_in[2];
    const float* ev_vu      = (const float*)d_in[3];
    const float* Watt       = (const float*)d_in[4];
    const float* Wb         = (const float*)d_in[5];
    const float* Wagg       = (const float*)d_in[6];
    const int*   edge_u     = (const int*)d_in[7];
    const int*   edge_i     = (const int*)d_in[8];
    const int*   uidx       = (const int*)d_in[9];
    const int*   ctx        = (const int*)d_in[10];
    float* out = (float*)d_out;

    // workspace layout (floats/ints, 4 B each)
    char* p = (char*)d_ws;
    float* u_msg     = (float*)p;  p += (size_t)N_USERS * D * 4;       // 25.6 MB
    float* V1        = (float*)p;  p += (size_t)N_ITEMS * D * 4;       // 12.8 MB (becomes Vf in place)
    int*   csr_u_idx = (int*)p;    p += (size_t)N_EDGES * 4;
    float* csr_u_val = (float*)p;  p += (size_t)N_EDGES * 4;
    int*   csr_i_idx = (int*)p;    p += (size_t)N_EDGES * 4;
    float* csr_i_val = (float*)p;  p += (size_t)N_EDGES * 4;           // +16 MB
    int*   cur_u     = (int*)p;    p += (size_t)N_USERS * 4;           // counts -> cursor
    int*   cur_i     = (int*)p;    p += (size_t)N_ITEMS * 4;
    unsigned int* ctrs = (unsigned int*)p; p += 2 * 4;                 // alloc counters
    int*   off_u     = (int*)p;    p += (size_t)N_USERS * 4;
    int*   off_i     = (int*)p;    p += (size_t)N_ITEMS * 4;
    // total ~55.8 MB

    // zero cnt arrays + counters (contiguous: cur_u, cur_i, ctrs)
    hipMemsetAsync(cur_u, 0, ((size_t)N_USERS + N_ITEMS + 2) * 4, stream);

    const int eblocks = (N_EDGES + 255) / 256;
    hist_kernel<<<eblocks, 256, 0, stream>>>(edge_u, edge_i, cur_u, cur_i);
    offsets_kernel<<<(N_USERS + 255) / 256, 256, 0, stream>>>(cur_u, off_u, N_USERS, &ctrs[0]);
    offsets_kernel<<<(N_ITEMS + 255) / 256, 256, 0, stream>>>(cur_i, off_i, N_ITEMS, &ctrs[1]);
    scatter_kernel<<<eblocks, 256, 0, stream>>>(edge_u, edge_i, ev_uv, ev_vu,
                                                cur_u, cur_i,
                                                csr_u_idx, csr_u_val,
                                                csr_i_idx, csr_i_val);

    const int ublocks = (N_USERS + 3) / 4;
    const int iblocks = (N_ITEMS + 3) / 4;

    // layer 1
    gather_kernel<<<ublocks, 256, 0, stream>>>(item_table, csr_u_idx, csr_u_val,
                                               off_u, cur_u, u_msg, N_USERS);
    gather_kernel<<<iblocks, 256, 0, stream>>>(u_msg, csr_i_idx, csr_i_val,
                                               off_i, cur_i, V1, N_ITEMS);
    // layer 2 (u_msg overwritten fully; final pass fuses combine, in-place -> V1 holds Vf)
    gather_kernel<<<ublocks, 256, 0, stream>>>(V1, csr_u_idx, csr_u_val,
                                               off_u, cur_u, u_msg, N_USERS);
    gather_final_kernel<<<iblocks, 256, 0, stream>>>(u_msg, csr_i_idx, csr_i_val,
                                                     off_i, cur_i, item_table, V1);

    // attention pooling + output (Vf == V1)
    phase2_kernel<<<BATCH / 4, 256, 0, stream>>>(user_table, V1, Watt, Wb, Wagg,
                                                 uidx, ctx, out);
}

// Round 3
// 651.237 us; speedup vs baseline: 5.5533x; 1.1369x over previous
//
#include <hip/hip_runtime.h>

#define N_USERS 100000
#define N_ITEMS 50001
#define N_EDGES 1000000
#define D 64
#define BATCH 4096
#define MAXLEN 50

// ---------------- CSR build ----------------

__global__ __launch_bounds__(256) void hist_kernel(
    const int* __restrict__ eu, const int* __restrict__ ei,
    int* __restrict__ cnt_u, int* __restrict__ cnt_i)
{
    int e = blockIdx.x * 256 + threadIdx.x;
    if (e < N_EDGES) {
        atomicAdd(&cnt_u[eu[e]], 1);
        atomicAdd(&cnt_i[ei[e]], 1);
    }
}

// bump-allocate contiguous segments per row (order-free "scan"):
// one atomic per wave; cnt[] becomes the running cursor (cur), off[] the base.
__global__ __launch_bounds__(256) void offsets_kernel(
    int* __restrict__ cnt /* in: counts, out: cursor */,
    int* __restrict__ off, int n, unsigned int* __restrict__ alloc_ctr)
{
    int i = blockIdx.x * 256 + threadIdx.x;
    int lane = threadIdx.x & 63;
    int c = (i < n) ? cnt[i] : 0;
    int pre = c;
#pragma unroll
    for (int o = 1; o < 64; o <<= 1) {
        int t = __shfl_up(pre, o, 64);
        if (lane >= o) pre += t;
    }
    int wave_total = __shfl(pre, 63, 64);
    unsigned int base = 0;
    if (lane == 63) base = atomicAdd(alloc_ctr, (unsigned int)wave_total);
    base = __shfl((int)base, 63, 64);
    int my_off = (int)base + pre - c;  // exclusive
    if (i < n) {
        off[i] = my_off;
        cnt[i] = my_off;  // becomes cursor for scatter
    }
}

// packed CSR entry: .x = src row idx, .y = fp32 bits of edge value (8B store)
__global__ __launch_bounds__(256) void scatter_kernel(
    const int* __restrict__ eu, const int* __restrict__ ei,
    const float* __restrict__ ev_uv, const float* __restrict__ ev_vu,
    int* __restrict__ cur_u, int* __restrict__ cur_i,
    int2* __restrict__ csr_u, int2* __restrict__ csr_i)
{
    int e = blockIdx.x * 256 + threadIdx.x;
    if (e < N_EDGES) {
        int u = eu[e], it = ei[e];
        int pu = atomicAdd(&cur_u[u], 1);
        int2 entu;
        entu.x = it;
        entu.y = __float_as_int(ev_uv[e]);
        csr_u[pu] = entu;
        int pi = atomicAdd(&cur_i[it], 1);
        int2 enti;
        enti.x = u;
        enti.y = __float_as_int(ev_vu[e]);
        csr_i[pi] = enti;
    }
}

// ---------------- gather spmm (no atomics) ----------------
// one wave per destination row, lane = feature dim; 4-wide unrolled edge loop
__device__ __forceinline__ float gather_row(
    const float* __restrict__ src, const int2* __restrict__ csr,
    int o, int e, int lane)
{
    float acc = 0.0f;
    for (int base = o; base < e; base += 64) {
        int n = min(64, e - base);
        int si = 0; float sv = 0.0f;
        if (lane < n) {
            int2 ent = csr[base + lane];
            si = ent.x;
            sv = __int_as_float(ent.y);
        }
        int j = 0;
        for (; j + 4 <= n; j += 4) {
            int r0 = __shfl(si, j + 0, 64);
            int r1 = __shfl(si, j + 1, 64);
            int r2 = __shfl(si, j + 2, 64);
            int r3 = __shfl(si, j + 3, 64);
            float v0 = __shfl(sv, j + 0, 64);
            float v1 = __shfl(sv, j + 1, 64);
            float v2 = __shfl(sv, j + 2, 64);
            float v3 = __shfl(sv, j + 3, 64);
            float x0 = src[(size_t)r0 * D + lane];
            float x1 = src[(size_t)r1 * D + lane];
            float x2 = src[(size_t)r2 * D + lane];
            float x3 = src[(size_t)r3 * D + lane];
            acc += v0 * x0;
            acc += v1 * x1;
            acc += v2 * x2;
            acc += v3 * x3;
        }
        for (; j < n; ++j) {
            int r = __shfl(si, j, 64);
            float v = __shfl(sv, j, 64);
            acc += v * src[(size_t)r * D + lane];
        }
    }
    return acc;
}

__global__ __launch_bounds__(256) void gather_kernel(
    const float* __restrict__ src, const int2* __restrict__ csr,
    const int* __restrict__ off, const int* __restrict__ cur,
    float* __restrict__ dst, int nrows)
{
    int w = (blockIdx.x * 256 + threadIdx.x) >> 6;
    int lane = threadIdx.x & 63;
    if (w >= nrows) return;
    float acc = gather_row(src, csr, off[w], cur[w], lane);
    dst[(size_t)w * D + lane] = acc;
}

// final pass: V2-gather fused with Vf = (V0+V1+V2)/3 + V0, in place over V1
__global__ __launch_bounds__(256) void gather_final_kernel(
    const float* __restrict__ src, const int2* __restrict__ csr,
    const int* __restrict__ off, const int* __restrict__ cur,
    const float* __restrict__ V0, float* __restrict__ V1)
{
    int w = (blockIdx.x * 256 + threadIdx.x) >> 6;
    int lane = threadIdx.x & 63;
    if (w >= N_ITEMS) return;
    float acc = gather_row(src, csr, off[w], cur[w], lane);
    size_t p = (size_t)w * D + lane;
    float v0 = V0[p];
    float v1 = V1[p];
    V1[p] = (v0 + v1 + acc) * (1.0f / 3.0f) + v0;
}

// ---------------- attention pooling ----------------

__device__ __forceinline__ float wave_sum64(float v) {
#pragma unroll
    for (int o = 1; o < 64; o <<= 1) v += __shfl_xor(v, o, 64);
    return v;
}

__global__ __launch_bounds__(256) void phase2_kernel(
    const float* __restrict__ user_table, const float* __restrict__ Vf,
    const float* __restrict__ Watt, const float* __restrict__ Wb,
    const float* __restrict__ Wagg, const int* __restrict__ uidx,
    const int* __restrict__ ctx, float* __restrict__ out)
{
    __shared__ __align__(16) float seqrow[4][64];
    __shared__ __align__(16) float xbuf[4][64];
    __shared__ __align__(16) float pooled_s[4][64];
    __shared__ int idxbuf[4][MAXLEN];

    const int tid = threadIdx.x;
    const int w = tid >> 6;
    const int lane = tid & 63;
    const int b = blockIdx.x * 4 + w;

    float wa[D], wg[D];
    {
        const float4* wr = (const float4*)(Watt + (size_t)lane * D);
        const float4* gr = (const float4*)(Wagg + (size_t)lane * D);
#pragma unroll
        for (int k = 0; k < 16; ++k) {
            float4 a = wr[k];
            float4 g = gr[k];
            wa[4 * k + 0] = a.x; wa[4 * k + 1] = a.y;
            wa[4 * k + 2] = a.z; wa[4 * k + 3] = a.w;
            wg[4 * k + 0] = g.x; wg[4 * k + 1] = g.y;
            wg[4 * k + 2] = g.z; wg[4 * k + 3] = g.w;
        }
    }
    float bias = Wb[lane];
    int uid = uidx[b];
    float id_e = user_table[(size_t)uid * D + lane];

    for (int l = 0; l < MAXLEN; ++l) {
        int ci = ctx[b * MAXLEN + l];
        if (lane == 0) idxbuf[w][l] = ci;
        float s = Vf[(size_t)ci * D + lane];
        seqrow[w][lane] = s;
        float acc0 = bias, acc1 = 0.f, acc2 = 0.f, acc3 = 0.f;
#pragma unroll
        for (int d = 0; d < D; d += 4) {
            float4 s4 = *(const float4*)&seqrow[w][d];
            acc0 += s4.x * wa[d + 0];
            acc1 += s4.y * wa[d + 1];
            acc2 += s4.z * wa[d + 2];
            acc3 += s4.w * wa[d + 3];
        }
        float key = tanhf(acc0 + acc1 + acc2 + acc3);
        float part = key * id_e;
        float rs = s;
        float att = part;
#pragma unroll
        for (int o = 1; o < 64; o <<= 1) {
            att += __shfl_xor(att, o, 64);
            rs += __shfl_xor(rs, o, 64);
        }
        float X = (rs == 0.0f) ? 0.0f : att;
        if (lane == 0) xbuf[w][l] = X;
    }

    float ex = (lane < MAXLEN) ? expf(xbuf[w][lane]) : 0.0f;
    float denom = wave_sum64(ex) + 1e-12f;
    if (lane < MAXLEN) xbuf[w][lane] = ex / denom;

    float pooled = 0.0f;
    for (int l = 0; l < MAXLEN; ++l) {
        int ci = idxbuf[w][l];
        float a = xbuf[w][l];
        pooled += a * Vf[(size_t)ci * D + lane];
    }
    pooled_s[w][lane] = pooled;

    float o0 = 0.f, o1 = 0.f, o2 = 0.f, o3 = 0.f;
#pragma unroll
    for (int d = 0; d < D; d += 4) {
        float4 p4 = *(const float4*)&pooled_s[w][d];
        o0 += p4.x * wg[d + 0];
        o1 += p4.y * wg[d + 1];
        o2 += p4.z * wg[d + 2];
        o3 += p4.w * wg[d + 3];
    }
    float outv = o0 + o1 + o2 + o3;
    out[(size_t)b * D + lane] = 0.5f * id_e + 0.5f * outv;
}

// ---------------- launch ----------------

extern "C" void kernel_launch(void* const* d_in, const int* in_sizes, int n_in,
                              void* d_out, int out_size, void* d_ws, size_t ws_size,
                              hipStream_t stream)
{
    const float* user_table = (const float*)d_in[0];
    const float* item_table = (const float*)d_in[1];
    const float* ev_uv      = (const float*)d_in[2];
    const float* ev_vu      = (const float*)d_in[3];
    const float* Watt       = (const float*)d_in[4];
    const float* Wb         = (const float*)d_in[5];
    const float* Wagg       = (const float*)d_in[6];
    const int*   edge_u     = (const int*)d_in[7];
    const int*   edge_i     = (const int*)d_in[8];
    const int*   uidx       = (const int*)d_in[9];
    const int*   ctx        = (const int*)d_in[10];
    float* out = (float*)d_out;

    // workspace layout
    char* p = (char*)d_ws;
    float* u_msg  = (float*)p;  p += (size_t)N_USERS * D * 4;   // 25.6 MB
    float* V1     = (float*)p;  p += (size_t)N_ITEMS * D * 4;   // 12.8 MB (becomes Vf)
    int2*  csr_u  = (int2*)p;   p += (size_t)N_EDGES * 8;       // 8 MB
    int2*  csr_i  = (int2*)p;   p += (size_t)N_EDGES * 8;       // 8 MB
    int*   cur_u  = (int*)p;    p += (size_t)N_USERS * 4;       // counts -> cursor
    int*   cur_i  = (int*)p;    p += (size_t)N_ITEMS * 4;
    unsigned int* ctrs = (unsigned int*)p; p += 2 * 4;
    int*   off_u  = (int*)p;    p += (size_t)N_USERS * 4;
    int*   off_i  = (int*)p;    p += (size_t)N_ITEMS * 4;

    // zero cnt arrays + counters (contiguous: cur_u, cur_i, ctrs)
    hipMemsetAsync(cur_u, 0, ((size_t)N_USERS + N_ITEMS + 2) * 4, stream);

    const int eblocks = (N_EDGES + 255) / 256;
    hist_kernel<<<eblocks, 256, 0, stream>>>(edge_u, edge_i, cur_u, cur_i);
    offsets_kernel<<<(N_USERS + 255) / 256, 256, 0, stream>>>(cur_u, off_u, N_USERS, &ctrs[0]);
    offsets_kernel<<<(N_ITEMS + 255) / 256, 256, 0, stream>>>(cur_i, off_i, N_ITEMS, &ctrs[1]);
    scatter_kernel<<<eblocks, 256, 0, stream>>>(edge_u, edge_i, ev_uv, ev_vu,
                                                cur_u, cur_i, csr_u, csr_i);

    const int ublocks = (N_USERS + 3) / 4;
    const int iblocks = (N_ITEMS + 3) / 4;

    // layer 1
    gather_kernel<<<ublocks, 256, 0, stream>>>(item_table, csr_u, off_u, cur_u, u_msg, N_USERS);
    gather_kernel<<<iblocks, 256, 0, stream>>>(u_msg, csr_i, off_i, cur_i, V1, N_ITEMS);
    // layer 2 (final pass fuses combine, in-place -> V1 holds Vf)
    gather_kernel<<<ublocks, 256, 0, stream>>>(V1, csr_u, off_u, cur_u, u_msg, N_USERS);
    gather_final_kernel<<<iblocks, 256, 0, stream>>>(u_msg, csr_i, off_i, cur_i, item_table, V1);

    // attention pooling + output (Vf == V1)
    phase2_kernel<<<BATCH / 4, 256, 0, stream>>>(user_table, V1, Watt, Wb, Wagg,
                                                 uidx, ctx, out);
}

// Round 4
// 617.210 us; speedup vs baseline: 5.8595x; 1.0551x over previous
//
#include <hip/hip_runtime.h>

#define N_USERS 100000
#define N_ITEMS 50001
#define N_EDGES 1000000
#define D 64
#define BATCH 4096
#define MAXLEN 50

// ---------- bf16 helpers (manual, RNE encode / exact decode) ----------
__device__ __forceinline__ float bf_lo(unsigned u) { return __uint_as_float(u << 16); }
__device__ __forceinline__ float bf_hi(unsigned u) { return __uint_as_float(u & 0xffff0000u); }
__device__ __forceinline__ unsigned bf_pack2(float a, float b) {
    unsigned ba = __float_as_uint(a);
    unsigned bb = __float_as_uint(b);
    ba += 0x7fffu + ((ba >> 16) & 1u);
    bb += 0x7fffu + ((bb >> 16) & 1u);
    return (ba >> 16) | (bb & 0xffff0000u);
}

// ---------------- CSR build ----------------

__global__ __launch_bounds__(256) void hist_kernel(
    const int* __restrict__ eu, const int* __restrict__ ei,
    int* __restrict__ cnt_u, int* __restrict__ cnt_i)
{
    int e = blockIdx.x * 256 + threadIdx.x;
    if (e < N_EDGES) {
        atomicAdd(&cnt_u[eu[e]], 1);
        atomicAdd(&cnt_i[ei[e]], 1);
    }
}

__global__ __launch_bounds__(256) void offsets_kernel(
    int* __restrict__ cnt /* in: counts, out: cursor */,
    int* __restrict__ off, int n, unsigned int* __restrict__ alloc_ctr)
{
    int i = blockIdx.x * 256 + threadIdx.x;
    int lane = threadIdx.x & 63;
    int c = (i < n) ? cnt[i] : 0;
    int pre = c;
#pragma unroll
    for (int o = 1; o < 64; o <<= 1) {
        int t = __shfl_up(pre, o, 64);
        if (lane >= o) pre += t;
    }
    int wave_total = __shfl(pre, 63, 64);
    unsigned int base = 0;
    if (lane == 63) base = atomicAdd(alloc_ctr, (unsigned int)wave_total);
    base = __shfl((int)base, 63, 64);
    int my_off = (int)base + pre - c;  // exclusive
    if (i < n) {
        off[i] = my_off;
        cnt[i] = my_off;  // becomes cursor for scatter
    }
}

// packed CSR entry: .x = src row idx, .y = fp32 bits of edge value
__global__ __launch_bounds__(256) void scatter_kernel(
    const int* __restrict__ eu, const int* __restrict__ ei,
    const float* __restrict__ ev_uv, const float* __restrict__ ev_vu,
    int* __restrict__ cur_u, int* __restrict__ cur_i,
    int2* __restrict__ csr_u, int2* __restrict__ csr_i)
{
    int e = blockIdx.x * 256 + threadIdx.x;
    if (e < N_EDGES) {
        int u = eu[e], it = ei[e];
        int pu = atomicAdd(&cur_u[u], 1);
        int2 entu;
        entu.x = it;
        entu.y = __float_as_int(ev_uv[e]);
        csr_u[pu] = entu;
        int pi = atomicAdd(&cur_i[it], 1);
        int2 enti;
        enti.x = u;
        enti.y = __float_as_int(ev_vu[e]);
        csr_i[pi] = enti;
    }
}

// ---------------- fp32 -> bf16 table convert ----------------
__global__ __launch_bounds__(256) void convert_kernel(
    const float* __restrict__ src, unsigned* __restrict__ dst, int npairs)
{
    int i = blockIdx.x * 256 + threadIdx.x;
    if (i < npairs) {
        float2 f = ((const float2*)src)[i];
        dst[i] = bf_pack2(f.x, f.y);
    }
}

// ---------------- gather spmm over bf16 rows ----------------
// one wave per dst row; half-wave per edge: lane = 32*h + c,
// lane accumulates features (2c, 2c+1) for edge-parity h.
// Out-of-range shfl sources carry si=0 / sv=0 -> harmless row-0, val-0 reads.
__device__ __forceinline__ void gather_row_bf(
    const unsigned* __restrict__ src, const int2* __restrict__ csr,
    int o, int e, int lane, int c, int h, float& A0, float& A1)
{
    float acc0 = 0.0f, acc1 = 0.0f;
    for (int base = o; base < e; base += 64) {
        int n = min(64, e - base);
        int si = 0; float sv = 0.0f;
        if (lane < n) {
            int2 ent = csr[base + lane];
            si = ent.x;
            sv = __int_as_float(ent.y);
        }
        int np = (n + 1) >> 1;  // pairs of edges
        int p = 0;
        for (; p + 2 <= np; p += 2) {
            int j = 2 * p;
            int r0 = __shfl(si, j + 0, 64), r1 = __shfl(si, j + 1, 64);
            int r2 = __shfl(si, j + 2, 64), r3 = __shfl(si, j + 3, 64);
            float v0 = __shfl(sv, j + 0, 64), v1 = __shfl(sv, j + 1, 64);
            float v2 = __shfl(sv, j + 2, 64), v3 = __shfl(sv, j + 3, 64);
            int ra = h ? r1 : r0; float va = h ? v1 : v0;
            int rb = h ? r3 : r2; float vb = h ? v3 : v2;
            unsigned ua = src[(size_t)ra * 32 + c];
            unsigned ub = src[(size_t)rb * 32 + c];
            acc0 += va * bf_lo(ua);
            acc1 += va * bf_hi(ua);
            acc0 += vb * bf_lo(ub);
            acc1 += vb * bf_hi(ub);
        }
        for (; p < np; ++p) {
            int j = 2 * p;
            int r0 = __shfl(si, j + 0, 64), r1 = __shfl(si, j + 1, 64);
            float v0 = __shfl(sv, j + 0, 64), v1 = __shfl(sv, j + 1, 64);
            int ra = h ? r1 : r0; float va = h ? v1 : v0;
            unsigned ua = src[(size_t)ra * 32 + c];
            acc0 += va * bf_lo(ua);
            acc1 += va * bf_hi(ua);
        }
    }
    A0 = acc0; A1 = acc1;
}

__global__ __launch_bounds__(256) void gather_bf_kernel(
    const unsigned* __restrict__ src, const int2* __restrict__ csr,
    const int* __restrict__ off, const int* __restrict__ cur,
    unsigned* __restrict__ dst, int nrows)
{
    int w = (blockIdx.x * 256 + threadIdx.x) >> 6;
    int lane = threadIdx.x & 63;
    if (w >= nrows) return;
    int c = lane & 31, h = lane >> 5;
    float a0, a1;
    gather_row_bf(src, csr, off[w], cur[w], lane, c, h, a0, a1);
    a0 += __shfl_xor(a0, 32, 64);
    a1 += __shfl_xor(a1, 32, 64);
    if (lane < 32)
        dst[(size_t)w * 32 + lane] = bf_pack2(a0, a1);
}

// final: V2-gather fused with Vf = (V0 + V1 + V2)/3 + V0; Vf fp32
__global__ __launch_bounds__(256) void gather_final_bf_kernel(
    const unsigned* __restrict__ src, const int2* __restrict__ csr,
    const int* __restrict__ off, const int* __restrict__ cur,
    const float* __restrict__ V0, const unsigned* __restrict__ V1bf,
    float* __restrict__ Vf)
{
    int w = (blockIdx.x * 256 + threadIdx.x) >> 6;
    int lane = threadIdx.x & 63;
    if (w >= N_ITEMS) return;
    int c = lane & 31, h = lane >> 5;
    float a0, a1;
    gather_row_bf(src, csr, off[w], cur[w], lane, c, h, a0, a1);
    a0 += __shfl_xor(a0, 32, 64);
    a1 += __shfl_xor(a1, 32, 64);
    if (lane < 32) {
        float2 v0 = *(const float2*)(V0 + (size_t)w * D + 2 * lane);
        unsigned u1 = V1bf[(size_t)w * 32 + lane];
        float2 r;
        r.x = (v0.x + bf_lo(u1) + a0) * (1.0f / 3.0f) + v0.x;
        r.y = (v0.y + bf_hi(u1) + a1) * (1.0f / 3.0f) + v0.y;
        *(float2*)(Vf + (size_t)w * D + 2 * lane) = r;
    }
}

// ---------------- attention pooling ----------------

__device__ __forceinline__ float wave_sum64(float v) {
#pragma unroll
    for (int o = 1; o < 64; o <<= 1) v += __shfl_xor(v, o, 64);
    return v;
}

__global__ __launch_bounds__(256) void phase2_kernel(
    const float* __restrict__ user_table, const float* __restrict__ Vf,
    const float* __restrict__ Watt, const float* __restrict__ Wb,
    const float* __restrict__ Wagg, const int* __restrict__ uidx,
    const int* __restrict__ ctx, float* __restrict__ out)
{
    __shared__ __align__(16) float seqrow[4][64];
    __shared__ __align__(16) float xbuf[4][64];
    __shared__ __align__(16) float pooled_s[4][64];
    __shared__ int idxbuf[4][MAXLEN];

    const int tid = threadIdx.x;
    const int w = tid >> 6;
    const int lane = tid & 63;
    const int b = blockIdx.x * 4 + w;

    float wa[D], wg[D];
    {
        const float4* wr = (const float4*)(Watt + (size_t)lane * D);
        const float4* gr = (const float4*)(Wagg + (size_t)lane * D);
#pragma unroll
        for (int k = 0; k < 16; ++k) {
            float4 a = wr[k];
            float4 g = gr[k];
            wa[4 * k + 0] = a.x; wa[4 * k + 1] = a.y;
            wa[4 * k + 2] = a.z; wa[4 * k + 3] = a.w;
            wg[4 * k + 0] = g.x; wg[4 * k + 1] = g.y;
            wg[4 * k + 2] = g.z; wg[4 * k + 3] = g.w;
        }
    }
    float bias = Wb[lane];
    int uid = uidx[b];
    float id_e = user_table[(size_t)uid * D + lane];

    for (int l = 0; l < MAXLEN; ++l) {
        int ci = ctx[b * MAXLEN + l];
        if (lane == 0) idxbuf[w][l] = ci;
        float s = Vf[(size_t)ci * D + lane];
        seqrow[w][lane] = s;
        float acc0 = bias, acc1 = 0.f, acc2 = 0.f, acc3 = 0.f;
#pragma unroll
        for (int d = 0; d < D; d += 4) {
            float4 s4 = *(const float4*)&seqrow[w][d];
            acc0 += s4.x * wa[d + 0];
            acc1 += s4.y * wa[d + 1];
            acc2 += s4.z * wa[d + 2];
            acc3 += s4.w * wa[d + 3];
        }
        float key = tanhf(acc0 + acc1 + acc2 + acc3);
        float part = key * id_e;
        float rs = s;
        float att = part;
#pragma unroll
        for (int o = 1; o < 64; o <<= 1) {
            att += __shfl_xor(att, o, 64);
            rs += __shfl_xor(rs, o, 64);
        }
        float X = (rs == 0.0f) ? 0.0f : att;
        if (lane == 0) xbuf[w][l] = X;
    }

    float ex = (lane < MAXLEN) ? expf(xbuf[w][lane]) : 0.0f;
    float denom = wave_sum64(ex) + 1e-12f;
    if (lane < MAXLEN) xbuf[w][lane] = ex / denom;

    float pooled = 0.0f;
    for (int l = 0; l < MAXLEN; ++l) {
        int ci = idxbuf[w][l];
        float a = xbuf[w][l];
        pooled += a * Vf[(size_t)ci * D + lane];
    }
    pooled_s[w][lane] = pooled;

    float o0 = 0.f, o1 = 0.f, o2 = 0.f, o3 = 0.f;
#pragma unroll
    for (int d = 0; d < D; d += 4) {
        float4 p4 = *(const float4*)&pooled_s[w][d];
        o0 += p4.x * wg[d + 0];
        o1 += p4.y * wg[d + 1];
        o2 += p4.z * wg[d + 2];
        o3 += p4.w * wg[d + 3];
    }
    float outv = o0 + o1 + o2 + o3;
    out[(size_t)b * D + lane] = 0.5f * id_e + 0.5f * outv;
}

// ---------------- launch ----------------

extern "C" void kernel_launch(void* const* d_in, const int* in_sizes, int n_in,
                              void* d_out, int out_size, void* d_ws, size_t ws_size,
                              hipStream_t stream)
{
    const float* user_table = (const float*)d_in[0];
    const float* item_table = (const float*)d_in[1];
    const float* ev_uv      = (const float*)d_in[2];
    const float* ev_vu      = (const float*)d_in[3];
    const float* Watt       = (const float*)d_in[4];
    const float* Wb         = (const float*)d_in[5];
    const float* Wagg       = (const float*)d_in[6];
    const int*   edge_u     = (const int*)d_in[7];
    const int*   edge_i     = (const int*)d_in[8];
    const int*   uidx       = (const int*)d_in[9];
    const int*   ctx        = (const int*)d_in[10];
    float* out = (float*)d_out;

    // workspace layout (bf16 rows = 32 uints = 128 B)
    char* p = (char*)d_ws;
    unsigned* it_bf    = (unsigned*)p; p += (size_t)N_ITEMS * 32 * 4;   // 6.4 MB
    unsigned* u_msg_bf = (unsigned*)p; p += (size_t)N_USERS * 32 * 4;   // 12.8 MB
    unsigned* V1_bf    = (unsigned*)p; p += (size_t)N_ITEMS * 32 * 4;   // 6.4 MB
    float*    Vf       = (float*)p;    p += (size_t)N_ITEMS * D * 4;    // 12.8 MB
    int2*     csr_u    = (int2*)p;     p += (size_t)N_EDGES * 8;        // 8 MB
    int2*     csr_i    = (int2*)p;     p += (size_t)N_EDGES * 8;        // 8 MB
    int*      cur_u    = (int*)p;      p += (size_t)N_USERS * 4;
    int*      cur_i    = (int*)p;      p += (size_t)N_ITEMS * 4;
    unsigned int* ctrs = (unsigned int*)p; p += 2 * 4;
    int*      off_u    = (int*)p;      p += (size_t)N_USERS * 4;
    int*      off_i    = (int*)p;      p += (size_t)N_ITEMS * 4;
    // ~55.6 MB total

    hipMemsetAsync(cur_u, 0, ((size_t)N_USERS + N_ITEMS + 2) * 4, stream);

    const int eblocks = (N_EDGES + 255) / 256;
    convert_kernel<<<(N_ITEMS * 32 + 255) / 256, 256, 0, stream>>>(
        item_table, it_bf, N_ITEMS * 32);
    hist_kernel<<<eblocks, 256, 0, stream>>>(edge_u, edge_i, cur_u, cur_i);
    offsets_kernel<<<(N_USERS + 255) / 256, 256, 0, stream>>>(cur_u, off_u, N_USERS, &ctrs[0]);
    offsets_kernel<<<(N_ITEMS + 255) / 256, 256, 0, stream>>>(cur_i, off_i, N_ITEMS, &ctrs[1]);
    scatter_kernel<<<eblocks, 256, 0, stream>>>(edge_u, edge_i, ev_uv, ev_vu,
                                                cur_u, cur_i, csr_u, csr_i);

    const int ublocks = (N_USERS + 3) / 4;
    const int iblocks = (N_ITEMS + 3) / 4;

    // layer 1
    gather_bf_kernel<<<ublocks, 256, 0, stream>>>(it_bf, csr_u, off_u, cur_u, u_msg_bf, N_USERS);
    gather_bf_kernel<<<iblocks, 256, 0, stream>>>(u_msg_bf, csr_i, off_i, cur_i, V1_bf, N_ITEMS);
    // layer 2 (+ fused combine -> Vf fp32)
    gather_bf_kernel<<<ublocks, 256, 0, stream>>>(V1_bf, csr_u, off_u, cur_u, u_msg_bf, N_USERS);
    gather_final_bf_kernel<<<iblocks, 256, 0, stream>>>(u_msg_bf, csr_i, off_i, cur_i,
                                                        item_table, V1_bf, Vf);

    // attention pooling + output
    phase2_kernel<<<BATCH / 4, 256, 0, stream>>>(user_table, Vf, Watt, Wb, Wagg,
                                                 uidx, ctx, out);
}